// Round 1
// baseline (529.474 us; speedup 1.0000x reference)
//
#include <hip/hip_runtime.h>
#include <stdint.h>

#define B 8
#define NN 2000
#define EG 64000
#define FF 1024
#define DD 128
#define BK 32
#define NCHUNK 125   // aggreduce chunks per graph (16 nodes each)
#define CG 5         // chunk groups for gsum tree (25 chunks each)

// k_prep block ranges
#define NB_CONV 32000   // 16*2000*1024/4 float4 / 256
#define NB_WT   2048    // 32*32*2 tiles
#define NB_DEG  4000    // 16*64000 / 256
// k_gemm_fill block ranges
#define NB_GEMM 2048
#define NB_FILL 4000

typedef short short8 __attribute__((ext_vector_type(8)));
typedef float f32x4 __attribute__((ext_vector_type(4)));
typedef float f32x2 __attribute__((ext_vector_type(2)));

__device__ __forceinline__ unsigned short f2bf(float f) {
    union { float f; unsigned int u; } v; v.f = f;
    unsigned int u = v.u;
    unsigned int r = u + 0x7FFFu + ((u >> 16) & 1u);
    return (unsigned short)(r >> 16);
}
__device__ __forceinline__ float leaky(float v) { return v >= 0.0f ? v : 0.01f * v; }

// unpack uint4 = 8 bf16, packed fma into r[0..3] (f32x2 lanes -> v_pk_fma_f32)
__device__ __forceinline__ void acc8p(f32x2* __restrict__ r, float w, uint4 v) {
    union { unsigned int u; float f; } c;
    f32x2 wv = {w, w};
    f32x2 h;
    c.u = v.x << 16;          h.x = c.f;
    c.u = v.x & 0xffff0000u;  h.y = c.f;
    r[0] += wv * h;
    c.u = v.y << 16;          h.x = c.f;
    c.u = v.y & 0xffff0000u;  h.y = c.f;
    r[1] += wv * h;
    c.u = v.z << 16;          h.x = c.f;
    c.u = v.z & 0xffff0000u;  h.y = c.f;
    r[2] += wv * h;
    c.u = v.w << 16;          h.x = c.f;
    c.u = v.w & 0xffff0000u;  h.y = c.f;
    r[3] += wv * h;
}

// ---------------- fused prep: convx + wT transpose + degcount ----------------
// deg (int) must be zeroed beforehand (hipMemsetAsync node).
__global__ void k_prep(const float* __restrict__ x_a, const float* __restrict__ x_b,
                       unsigned short* __restrict__ xb,
                       const float* __restrict__ Wg_a, const float* __restrict__ Wg_b,
                       unsigned short* __restrict__ wT,
                       const int* __restrict__ ei_a, const int* __restrict__ ei_b,
                       int* __restrict__ degi) {
    int blk = blockIdx.x;
    int tid = threadIdx.x;
    __shared__ float tile[32][33];
    if (blk < NB_CONV) {
        // convert x1,x2 fp32 -> bf16 (exact multiple: no bound check)
        int i = blk * 256 + tid;
        float4 v = (i < NB_CONV * 128) ? ((const float4*)x_a)[i]
                                       : ((const float4*)x_b)[i - NB_CONV * 128];
        ushort4 o;
        o.x = f2bf(v.x); o.y = f2bf(v.y); o.z = f2bf(v.z); o.w = f2bf(v.w);
        ((ushort4*)xb)[i] = o;
    } else if (blk < NB_CONV + NB_WT) {
        // transpose+convert Wg -> wT[n][k] bf16
        int b2 = blk - NB_CONV;
        int z = b2 >> 10, rem = b2 & 1023;
        int by = rem >> 5, bx = rem & 31;
        int tx = tid & 31, ty = tid >> 5;  // 32 x 8
        int k0 = by * 32, n0 = bx * 32;
        const float* Wg = z ? Wg_b : Wg_a;
        unsigned short* o = wT + (size_t)z * FF * FF;
#pragma unroll
        for (int r = 0; r < 4; ++r) {
            int row = ty + r * 8;
            tile[row][tx] = Wg[(k0 + row) * FF + n0 + tx];
        }
        __syncthreads();
#pragma unroll
        for (int r = 0; r < 4; ++r) {
            int row = ty + r * 8;
            o[(n0 + row) * FF + k0 + tx] = f2bf(tile[tx][row]);
        }
    } else {
        // in-degree count (exact multiple: no bound check)
        int i = (blk - NB_CONV - NB_WT) * 256 + tid;
        int g = i / EG, e = i - g * EG;
        const int* ei = (g < B) ? (ei_a + (size_t)g * 2 * EG)
                                : (ei_b + (size_t)(g - B) * 2 * EG);
        int t = ei[EG + e];
        atomicAdd(&degi[g * NN + t], 1);
    }
}

// per-graph exclusive scan of in-degree -> CSR offsets, cursor init, dinv
__global__ void k_scan(const int* __restrict__ degi, int* __restrict__ csr_off,
                       int* __restrict__ cursor, float* __restrict__ dinv) {
    int g = blockIdx.x, t = threadIdx.x;
    __shared__ int part[256];
    int loc[8];
    int s = 0;
#pragma unroll
    for (int i = 0; i < 8; ++i) {
        int n = t * 8 + i;
        int c = (n < NN) ? degi[g * NN + n] : 0;
        if (n < NN) dinv[g * NN + n] = rsqrtf((float)(c + 1));  // +1 self loop
        loc[i] = s;
        s += c;
    }
    part[t] = s;
    __syncthreads();
    for (int off = 1; off < 256; off <<= 1) {
        int v = (t >= off) ? part[t - off] : 0;
        __syncthreads();
        part[t] += v;
        __syncthreads();
    }
    int base = part[t] - s;
#pragma unroll
    for (int i = 0; i < 8; ++i) {
        int n = t * 8 + i;
        if (n < NN) {
            int o = base + loc[i];
            csr_off[g * (NN + 1) + n] = o;
            cursor[g * NN + n] = o;
        }
    }
    if (t == 255) csr_off[g * (NN + 1) + NN] = part[255];
}

// ---------------- fused GEMM + fillcsr ----------------
// blocks [0, NB_GEMM): bf16 MFMA GEMM (global_load_lds staging, XCD remap)
// blocks [NB_GEMM, NB_GEMM+NB_FILL): CSR fill (latency-bound, hides under MFMA)
__launch_bounds__(256) __global__
void k_gemm_fill(const unsigned short* __restrict__ Abf, const unsigned short* __restrict__ wT,
                 unsigned short* __restrict__ Hbf,
                 const int* __restrict__ ei_a, const int* __restrict__ ei_b,
                 int* __restrict__ cursor, const float* __restrict__ dinv,
                 int2* __restrict__ epk) {
    int blk = blockIdx.x;
    __shared__ __align__(16) unsigned short As[128 * BK];
    __shared__ __align__(16) unsigned short Bs[128 * BK];
    if (blk >= NB_GEMM) {
        // ---- fillcsr ----
        int i = (blk - NB_GEMM) * 256 + threadIdx.x;
        int g = i / EG, e = i - g * EG;
        const int* ei = (g < B) ? (ei_a + (size_t)g * 2 * EG)
                                : (ei_b + (size_t)(g - B) * 2 * EG);
        int s = ei[e];
        int t = ei[EG + e];
        int pos = atomicAdd(&cursor[g * NN + t], 1);
        int2 p;
        p.x = s;
        p.y = __float_as_int(dinv[g * NN + s] * dinv[g * NN + t]);
        epk[(size_t)g * EG + pos] = p;
        return;
    }
    // ---- GEMM: blk bits [2:0]=XCD slot (m-tile low), [5:3]=n-tile, [10:6]=m-group
    int mt = ((blk >> 6) << 3) | (blk & 7);
    int nt = (blk >> 3) & 7;
    if (mt >= 250) return;
    int m0 = mt * 128, n0 = nt * 128;
    const unsigned short* Bbf = (mt >= 125) ? (wT + (size_t)FF * FF) : wT;

    int tid = threadIdx.x;
    int lane = tid & 63, wave = tid >> 6;
    int wr = wave >> 1, wc = wave & 1;
    int q = lane >> 4, l15 = lane & 15;
    int lr = lane >> 2, lc = lane & 3;

    f32x4 acc[4][4];
#pragma unroll
    for (int i = 0; i < 4; ++i)
#pragma unroll
        for (int j = 0; j < 4; ++j) acc[i][j] = (f32x4){0.f, 0.f, 0.f, 0.f};

    for (int kt = 0; kt < 32; ++kt) {
        int kb = kt * BK;
#pragma unroll
        for (int p = 0; p < 2; ++p) {
            int rbase = p * 64 + wave * 16;      // wave-uniform
            int r = rbase + lr;                  // per-lane global row
            __builtin_amdgcn_global_load_lds(
                (const __attribute__((address_space(1))) unsigned int*)
                    &Abf[(size_t)(m0 + r) * FF + kb + lc * 8],
                (__attribute__((address_space(3))) unsigned int*)&As[rbase * BK],
                16, 0, 0);
            __builtin_amdgcn_global_load_lds(
                (const __attribute__((address_space(1))) unsigned int*)
                    &Bbf[(size_t)(n0 + r) * FF + kb + lc * 8],
                (__attribute__((address_space(3))) unsigned int*)&Bs[rbase * BK],
                16, 0, 0);
        }
        __syncthreads();
        short8 fa[4], fb[4];
#pragma unroll
        for (int i = 0; i < 4; ++i)
            fa[i] = *(const short8*)&As[(wr * 64 + i * 16 + l15) * BK + q * 8];
#pragma unroll
        for (int j = 0; j < 4; ++j)
            fb[j] = *(const short8*)&Bs[(wc * 64 + j * 16 + l15) * BK + q * 8];
#pragma unroll
        for (int i = 0; i < 4; ++i)
#pragma unroll
            for (int j = 0; j < 4; ++j)
                acc[i][j] = __builtin_amdgcn_mfma_f32_16x16x32_bf16(fa[i], fb[j], acc[i][j], 0, 0, 0);
        __syncthreads();
    }
#pragma unroll
    for (int i = 0; i < 4; ++i) {
#pragma unroll
        for (int j = 0; j < 4; ++j) {
            int n = n0 + wc * 64 + j * 16 + l15;
#pragma unroll
            for (int v = 0; v < 4; ++v) {
                int m = m0 + wr * 64 + i * 16 + q * 4 + v;
                Hbf[(size_t)m * FF + n] = f2bf(acc[i][j][v]);
            }
        }
    }
}

// ---------------- fused aggregation + bias + leaky + node-sum ----------------
// Feature-half phasing: grid = 4*1000 blocks, phase = blk/1000.
// half = phase&1, graph-set = phase>>1. XCD = blk&7 -> per-XCD working set =
// 2.05MB H-half + 0.5MB epk < 4MB L2. f32x2 math; edge stream software-pipelined.
__launch_bounds__(256) __global__
void k_aggreduce(const unsigned short* __restrict__ Hbf, const int* __restrict__ csr_off,
                 const int2* __restrict__ epk, const float* __restrict__ dinv,
                 const float* __restrict__ bg_a, const float* __restrict__ bg_b,
                 float* __restrict__ part) {
    int blk = blockIdx.x;
    int phase = blk / 1000;
    int bp = blk - phase * 1000;
    int half = phase & 1;
    int g = (phase >> 1) * 8 + (bp & 7);
    int chunk = bp >> 3;         // 0..124
    int tid = threadIdx.x;
    int team = tid >> 6;         // 0..3
    int lane = tid & 63;
    int f0 = half * 512 + lane * 8;
    int n0 = chunk * 16 + team * 4;
    const unsigned short* Hb = Hbf + (size_t)g * NN * FF;
    const int2* ep = epk + (size_t)g * EG;
    const float* bg = (g < B) ? bg_a : bg_b;

    f32x2 bgv[4];
#pragma unroll
    for (int i = 0; i < 4; ++i) bgv[i] = (f32x2){bg[f0 + 2 * i], bg[f0 + 2 * i + 1]};
    f32x2 bsum[4];
#pragma unroll
    for (int i = 0; i < 4; ++i) bsum[i] = (f32x2){0.f, 0.f};

    for (int nn = 0; nn < 4; ++nn) {
        int n = n0 + nn;
        float dn = dinv[g * NN + n];
        int beg = csr_off[g * (NN + 1) + n];
        int end = csr_off[g * (NN + 1) + n + 1];
        f32x2 racc[4];
#pragma unroll
        for (int i = 0; i < 4; ++i) racc[i] = (f32x2){0.f, 0.f};
        {   // self-loop (weight 1/deg)
            uint4 sv = *(const uint4*)&Hb[(n << 10) + f0];
            acc8p(racc, dn * dn, sv);
        }
        int j = beg;
        int2 pe0, pe1, pe2, pe3;
        if (j + 4 <= end) { pe0 = ep[j]; pe1 = ep[j + 1]; pe2 = ep[j + 2]; pe3 = ep[j + 3]; }
        for (; j + 8 <= end; j += 4) {
            int2 e0 = pe0, e1 = pe1, e2 = pe2, e3 = pe3;
            pe0 = ep[j + 4]; pe1 = ep[j + 5]; pe2 = ep[j + 6]; pe3 = ep[j + 7];
            uint4 v0 = *(const uint4*)&Hb[(e0.x << 10) + f0];
            uint4 v1 = *(const uint4*)&Hb[(e1.x << 10) + f0];
            uint4 v2 = *(const uint4*)&Hb[(e2.x << 10) + f0];
            uint4 v3 = *(const uint4*)&Hb[(e3.x << 10) + f0];
            acc8p(racc, __int_as_float(e0.y), v0);
            acc8p(racc, __int_as_float(e1.y), v1);
            acc8p(racc, __int_as_float(e2.y), v2);
            acc8p(racc, __int_as_float(e3.y), v3);
        }
        if (j + 4 <= end) {
            uint4 v0 = *(const uint4*)&Hb[(pe0.x << 10) + f0];
            uint4 v1 = *(const uint4*)&Hb[(pe1.x << 10) + f0];
            uint4 v2 = *(const uint4*)&Hb[(pe2.x << 10) + f0];
            uint4 v3 = *(const uint4*)&Hb[(pe3.x << 10) + f0];
            acc8p(racc, __int_as_float(pe0.y), v0);
            acc8p(racc, __int_as_float(pe1.y), v1);
            acc8p(racc, __int_as_float(pe2.y), v2);
            acc8p(racc, __int_as_float(pe3.y), v3);
            j += 4;
        }
        for (; j < end; ++j) {
            int2 e = ep[j];
            uint4 v = *(const uint4*)&Hb[(e.x << 10) + f0];
            acc8p(racc, __int_as_float(e.y), v);
        }
#pragma unroll
        for (int i = 0; i < 4; ++i) {
            f32x2 t = racc[i] + bgv[i];
            bsum[i].x += leaky(t.x);
            bsum[i].y += leaky(t.y);
        }
    }

    // reduce across the 4 teams; stride-9 padding avoids bank conflicts
    __shared__ float red[3][64 * 9];
    if (team > 0) {
#pragma unroll
        for (int i = 0; i < 4; ++i) {
            red[team - 1][lane * 9 + 2 * i]     = bsum[i].x;
            red[team - 1][lane * 9 + 2 * i + 1] = bsum[i].y;
        }
    }
    __syncthreads();
    if (team == 0) {
        float* o = part + ((size_t)g * NCHUNK + chunk) * FF + f0;
        float r[8];
#pragma unroll
        for (int i = 0; i < 4; ++i) {
            r[2 * i]     = bsum[i].x;
            r[2 * i + 1] = bsum[i].y;
        }
#pragma unroll
        for (int t = 0; t < 3; ++t)
#pragma unroll
            for (int i = 0; i < 8; ++i) r[i] += red[t][lane * 9 + i];
        float4 a = {r[0], r[1], r[2], r[3]};
        float4 c = {r[4], r[5], r[6], r[7]};
        *(float4*)&o[0] = a;
        *(float4*)&o[4] = c;
    }
}

// tree level 1: sum 25 chunks -> part2[g][cg][f]
__global__ void k_gsum1(const float* __restrict__ part, float* __restrict__ part2) {
    int blk = blockIdx.x;               // g*20 + fq*5 + cg
    int g = blk / 20;
    int rem = blk - g * 20;
    int fq = rem / CG, cg = rem - fq * CG;
    int f = fq * 256 + threadIdx.x;
    const float* p = part + (size_t)g * NCHUNK * FF + (size_t)cg * 25 * FF + f;
    float s = 0.f;
#pragma unroll 5
    for (int c = 0; c < 25; ++c) s += p[(size_t)c * FF];
    part2[((size_t)g * CG + cg) * FF + f] = s;
}

// fc: sum 5 partials in LDS + sliced GEMV + leaky
// 512 threads: 4 f-slices of 256 each (serial depth 1024 -> 256), LDS reduce.
__launch_bounds__(512) __global__
void k_fc(const float* __restrict__ part2, const float* __restrict__ Wf_a,
          const float* __restrict__ bf_a, const float* __restrict__ Wf_b,
          const float* __restrict__ bf_b, float* __restrict__ g12) {
    int g = blockIdx.x, t = threadIdx.x;   // 512 threads
    int d = t & 127, slice = t >> 7;       // slice = 0..3
    __shared__ float gs[FF];
    __shared__ float red[4][DD];
    const float* p = part2 + (size_t)g * CG * FF;
#pragma unroll
    for (int i = 0; i < 2; ++i) {
        int f = i * 512 + t;
        float s = 0.f;
#pragma unroll
        for (int c = 0; c < CG; ++c) s += p[(size_t)c * FF + f];
        gs[f] = s;
    }
    __syncthreads();
    const float* Wf = (g < B) ? Wf_a : Wf_b;
    const float* bfv = (g < B) ? bf_a : bf_b;
    float acc = 0.f;
    int fbase = slice * 256;
#pragma unroll 8
    for (int ff = 0; ff < 256; ++ff) {
        int f = fbase + ff;
        acc += gs[f] * Wf[f * DD + d];
    }
    red[slice][d] = acc;
    __syncthreads();
    if (t < DD) {
        float a = red[0][t] + red[1][t] + red[2][t] + red[3][t];
        a = a * (1.0f / (float)NN) + bfv[t];
        g12[g * DD + t] = leaky(a);
    }
}

__launch_bounds__(256) __global__
void k_head(const float* __restrict__ g, const float* __restrict__ W1, const float* __restrict__ b1,
            const float* __restrict__ W2, const float* __restrict__ b2,
            const float* __restrict__ Wo, const float* __restrict__ bo, float* __restrict__ out) {
    __shared__ float xc[8][256];
    __shared__ float l1[8][256];
    __shared__ float l2[8][64];
    int t = threadIdx.x;
#pragma unroll
    for (int i = 0; i < 8; ++i) {
        int idx = i * 256 + t;
        int b = idx >> 8, j = idx & 255;
        xc[b][j] = (j < DD) ? g[b * DD + j] : g[B * DD + b * DD + (j - DD)];
    }
    __syncthreads();
    {
        int j = t;
        float a[8];
#pragma unroll
        for (int b = 0; b < 8; ++b) a[b] = b1[j];
        for (int k = 0; k < 256; ++k) {
            float w = W1[k * 256 + j];
#pragma unroll
            for (int b = 0; b < 8; ++b) a[b] += xc[b][k] * w;
        }
#pragma unroll
        for (int b = 0; b < 8; ++b) l1[b][j] = leaky(a[b]);
    }
    __syncthreads();
    if (t < 64) {
        int j = t;
        float a[8];
#pragma unroll
        for (int b = 0; b < 8; ++b) a[b] = b2[j];
        for (int k = 0; k < 256; ++k) {
            float w = W2[k * 64 + j];
#pragma unroll
            for (int b = 0; b < 8; ++b) a[b] += l1[b][k] * w;
        }
#pragma unroll
        for (int b = 0; b < 8; ++b) l2[b][j] = leaky(a[b]);
    }
    __syncthreads();
    if (t < 8) {
        float a = bo[0];
        for (int k = 0; k < 64; ++k) a += l2[t][k] * Wo[k];
        out[t] = 1.0f / (1.0f + expf(-a));
    }
}

extern "C" void kernel_launch(void* const* d_in, const int* in_sizes, int n_in,
                              void* d_out, int out_size, void* d_ws, size_t ws_size,
                              hipStream_t stream) {
    const float* x1  = (const float*)d_in[0];
    const int*   ei1 = (const int*)d_in[1];
    const float* x2  = (const float*)d_in[2];
    const int*   ei2 = (const int*)d_in[3];
    const float* Wg1 = (const float*)d_in[4];
    const float* bg1 = (const float*)d_in[5];
    const float* Wf1 = (const float*)d_in[6];
    const float* bf1 = (const float*)d_in[7];
    const float* Wg2 = (const float*)d_in[8];
    const float* bg2 = (const float*)d_in[9];
    const float* Wf2 = (const float*)d_in[10];
    const float* bf2 = (const float*)d_in[11];
    const float* W1  = (const float*)d_in[12];
    const float* b1  = (const float*)d_in[13];
    const float* W2  = (const float*)d_in[14];
    const float* b2  = (const float*)d_in[15];
    const float* Wo  = (const float*)d_in[16];
    const float* bo  = (const float*)d_in[17];
    float* out = (float*)d_out;

    // ---- batched (NG=16) workspace layout ----
    auto align = [](size_t v) { return (v + 255) & ~(size_t)255; };
    size_t need = 0;
    size_t o_deg  = need; need += align((size_t)16 * NN * 4);
    size_t o_dinv = need; need += align((size_t)16 * NN * 4);
    size_t o_csr  = need; need += align((size_t)16 * (NN + 1) * 4);
    size_t o_cur  = need; need += align((size_t)16 * NN * 4);
    size_t o_epk  = need; need += align((size_t)16 * EG * 8);
    size_t o_xbf  = need; need += align((size_t)16 * NN * FF * 2);
    size_t o_wT   = need; need += align((size_t)2 * FF * FF * 2);
    size_t o_hbf  = need; need += align((size_t)16 * NN * FF * 2);
    size_t o_part = need; need += align((size_t)16 * NCHUNK * FF * 4);
    size_t o_pt2  = need; need += align((size_t)16 * CG * FF * 4);
    size_t o_g12  = need; need += align((size_t)16 * DD * 4);
    (void)need;  // ws_size has been >= need (~152 MB) every round; batched path only

    char* w = (char*)d_ws;
    int* degi    = (int*)(w + o_deg);
    float* dinv  = (float*)(w + o_dinv);
    int* csr     = (int*)(w + o_csr);
    int* cur     = (int*)(w + o_cur);
    int2* epk    = (int2*)(w + o_epk);
    unsigned short* xbf = (unsigned short*)(w + o_xbf);
    unsigned short* wT  = (unsigned short*)(w + o_wT);
    unsigned short* hbf = (unsigned short*)(w + o_hbf);
    float* part  = (float*)(w + o_part);
    float* part2 = (float*)(w + o_pt2);
    float* g12   = (float*)(w + o_g12);

    // 8 nodes total: memset + 7 kernels
    hipMemsetAsync(degi, 0, (size_t)16 * NN * 4, stream);
    k_prep<<<NB_CONV + NB_WT + NB_DEG, 256, 0, stream>>>(x1, x2, xbf, Wg1, Wg2, wT,
                                                         ei1, ei2, degi);
    k_scan<<<16, 256, 0, stream>>>(degi, csr, cur, dinv);
    k_gemm_fill<<<NB_GEMM + NB_FILL, 256, 0, stream>>>(xbf, wT, hbf, ei1, ei2, cur,
                                                       dinv, epk);
    k_aggreduce<<<4000, 256, 0, stream>>>(hbf, csr, epk, dinv, bg1, bg2, part);
    k_gsum1<<<16 * 20, 256, 0, stream>>>(part, part2);
    k_fc<<<16, 512, 0, stream>>>(part2, Wf1, bf1, Wf2, bf2, g12);
    k_head<<<1, 256, 0, stream>>>(g12, W1, b1, W2, b2, Wo, bo, out);
}